// Round 7
// baseline (339.537 us; speedup 1.0000x reference)
//
#include <hip/hip_runtime.h>

// Problem constants (fixed by setup_inputs)
#define T_LEN 128
#define NB_BINS 15

// ---------------------------------------------------------------------------
// R3's fused kernel, verbatim: 4 lanes per sequence, dense 64B L loads,
// fast intrinsics, lane-specialized ll logs, double-buffer prefetch.
// Launched TWICE this round (slope experiment): pass1 -> d_ws, pass2 -> d_out.
// ---------------------------------------------------------------------------
__global__ __launch_bounds__(256) void k_fused(
    const float4* __restrict__ S4,
    const float4* __restrict__ Y4,
    const float4* __restrict__ M4,
    const float4* __restrict__ C4,
    const float4* __restrict__ L4,
    const float4* __restrict__ wgd4,
    const float4* __restrict__ wbd4,
    const float4* __restrict__ wgs4,
    const float4* __restrict__ wbs4,
    const float*  __restrict__ p_psi,
    const float*  __restrict__ p_gA,
    const float*  __restrict__ p_lsz,
    const float*  __restrict__ p_b0,
    const float*  __restrict__ p_bZ,
    const float*  __restrict__ p_bbins,
    const float*  __restrict__ p_bT,
    float* __restrict__ zf,
    float* __restrict__ zv,
    float* __restrict__ ll_out)
{
    __shared__ float sbins[NB_BINS];
    if (threadIdx.x < NB_BINS) sbins[threadIdx.x] = p_bbins[threadIdx.x];
    __syncthreads();

    const int gtid = blockIdx.x * blockDim.x + threadIdx.x;
    const int n = gtid >> 2;     // sequence index
    const int s = gtid & 3;      // sublane within 4-lane group

    // per-lane slices of the dynamic weights matching the dense L layout:
    // lane s covers elements [4s,4s+4) and [16+4s,16+4s+4)
    const float4 wga = wgd4[s],     wgb = wgd4[s + 4];
    const float4 wba = wbd4[s],     wbb = wbd4[s + 4];

    // scalar params
    const float psi  = p_psi[0];
    const float gA   = p_gA[0];
    const float e    = __expf(p_lsz[0]);
    const float sig2 = e * e;
    const float b0   = p_b0[0];
    const float bZ   = p_bZ[0];
    const float bT30 = p_bT[0] * (1.0f / 30.0f);
    const float psi2 = psi * psi;
    const float bZ2  = bZ * bZ;

    // static dots: each lane 4 elems of 16, butterfly over the 4-lane group
    float gs, bs;
    {
        const float4 c  = C4[n * 4 + s];
        const float4 wg = wgs4[s];
        const float4 wb = wbs4[s];
        gs = c.x * wg.x + c.y * wg.y + c.z * wg.z + c.w * wg.w;
        bs = c.x * wb.x + c.y * wb.y + c.z * wb.z + c.w * wb.w;
        gs += __shfl_xor(gs, 1, 64); gs += __shfl_xor(gs, 2, 64);
        bs += __shfl_xor(bs, 1, 64); bs += __shfl_xor(bs, 2, 64);
    }

    // L float4 index of (n, t=0); row t is lb + t*8; lane takes +s and +4+s
    const size_t lb  = (size_t)n * T_LEN * 8;
    const int    sbi = n * (T_LEN / 4);   // S/Y/M float4 chunk base

    // ---- chunk 0 load ----
    float4 Lc0 = L4[lb + 0*8 + s], Lc1 = L4[lb + 0*8 + 4 + s];
    float4 Lc2 = L4[lb + 1*8 + s], Lc3 = L4[lb + 1*8 + 4 + s];
    float4 Lc4 = L4[lb + 2*8 + s], Lc5 = L4[lb + 2*8 + 4 + s];
    float4 Lc6 = L4[lb + 3*8 + s], Lc7 = L4[lb + 3*8 + 4 + s];
    float4 sc = S4[sbi], yc = Y4[sbi], mc = M4[sbi];

    float zm = 0.0f, zvv = 1.0f, ll = 0.0f;

#define STEP(J, LA, LB, SS, YY, MM, PMOUT, PVOUT, PROBOUT) do {               \
        const float s_v = (SS), y_v = (YY), m_v = (MM);                       \
        float g   = LA.x*wga.x + LA.y*wga.y + LA.z*wga.z + LA.w*wga.w         \
                  + LB.x*wgb.x + LB.y*wgb.y + LB.z*wgb.z + LB.w*wgb.w;        \
        float bdv = LA.x*wba.x + LA.y*wba.y + LA.z*wba.z + LA.w*wba.w         \
                  + LB.x*wbb.x + LB.y*wbb.y + LB.z*wbb.z + LB.w*wbb.w;        \
        g   += __shfl_xor(g,   1, 64); g   += __shfl_xor(g,   2, 64);         \
        bdv += __shfl_xor(bdv, 1, 64); bdv += __shfl_xor(bdv, 2, 64);         \
        int cnt = (int)fmaxf(0.0f, fminf(14.0f,                               \
                      ceilf(fmaf(s_v, 3.0f, 7.5f)) - 1.0f));                  \
        const float be    = sbins[cnt];                                       \
        const float zpm   = psi * zm + gA * s_v + g + gs;                     \
        const float zpv   = psi2 * zvv + sig2;                                \
        float logit = b0 + bZ * zpm + be + bdv + bs                           \
                    + bT30 * (float)(4 * k + (J));                            \
        logit = fminf(fmaxf(logit, -20.0f), 20.0f);                           \
        const float prob  = __builtin_amdgcn_rcpf(1.0f + __expf(-logit));     \
        const float grad  = (y_v - prob) * bZ * m_v;                          \
        const float hess  = bZ2 * prob * (1.0f - prob) * m_v + 1e-6f;         \
        const float pvv   = __builtin_amdgcn_rcpf(                            \
                   __builtin_amdgcn_rcpf(zpv + 1e-8f) + hess);                \
        const float pmm   = zpm + pvv * grad;                                 \
        zm = pmm; zvv = pvv; PMOUT = pmm; PVOUT = pvv; PROBOUT = prob;        \
    } while (0)

    for (int k = 0; k < T_LEN / 4; ++k) {
        // ---- prefetch next chunk (clamped; redundant on last iter) ----
        const int kn = (k + 1 < T_LEN / 4) ? (k + 1) : k;
        const size_t lbn = lb + (size_t)(4 * kn) * 8;
        float4 Ln0 = L4[lbn + 0*8 + s], Ln1 = L4[lbn + 0*8 + 4 + s];
        float4 Ln2 = L4[lbn + 1*8 + s], Ln3 = L4[lbn + 1*8 + 4 + s];
        float4 Ln4 = L4[lbn + 2*8 + s], Ln5 = L4[lbn + 2*8 + 4 + s];
        float4 Ln6 = L4[lbn + 3*8 + s], Ln7 = L4[lbn + 3*8 + 4 + s];
        float4 snn = S4[sbi + kn], ynn = Y4[sbi + kn], mnn = M4[sbi + kn];

        // ---- compute 4 steps ----
        float pm0, pm1, pm2, pm3, pv0, pv1, pv2, pv3, pr0, pr1, pr2, pr3;
        STEP(0, Lc0, Lc1, sc.x, yc.x, mc.x, pm0, pv0, pr0);
        STEP(1, Lc2, Lc3, sc.y, yc.y, mc.y, pm1, pv1, pr1);
        STEP(2, Lc4, Lc5, sc.z, yc.z, mc.z, pm2, pv2, pr2);
        STEP(3, Lc6, Lc7, sc.w, yc.w, mc.w, pm3, pv3, pr3);

        // ---- coalesced store: lane s takes step 4k+s ----
        const float pmsel = (s == 0) ? pm0 : (s == 1) ? pm1 : (s == 2) ? pm2 : pm3;
        const float pvsel = (s == 0) ? pv0 : (s == 1) ? pv1 : (s == 2) ? pv2 : pv3;
        const size_t oidx = (size_t)n * T_LEN + 4 * k + s;
        zf[oidx] = pmsel;
        zv[oidx] = pvsel;

        // ---- ll: lane s evaluates only its own step's log terms ----
        {
            const float prs = (s == 0) ? pr0 : (s == 1) ? pr1 : (s == 2) ? pr2 : pr3;
            const float ys  = (s == 0) ? yc.x : (s == 1) ? yc.y : (s == 2) ? yc.z : yc.w;
            const float ms  = (s == 0) ? mc.x : (s == 1) ? mc.y : (s == 2) ? mc.z : mc.w;
            ll += (ys * __logf(prs + 1e-10f)
                 + (1.0f - ys) * __logf(1.0f - prs + 1e-10f)) * ms;
        }

        // ---- rotate buffers ----
        Lc0 = Ln0; Lc1 = Ln1; Lc2 = Ln2; Lc3 = Ln3;
        Lc4 = Ln4; Lc5 = Ln5; Lc6 = Ln6; Lc7 = Ln7;
        sc = snn; yc = ynn; mc = mnn;
    }
#undef STEP

    // ll: every lane owns distinct timesteps -> sum across the whole wave
    #pragma unroll
    for (int off = 1; off < 64; off <<= 1) ll += __shfl_xor(ll, off, 64);
    if ((threadIdx.x & 63) == 0) atomicAdd(ll_out, ll);
}

// ---------------------------------------------------------------------------
extern "C" void kernel_launch(void* const* d_in, const int* in_sizes, int n_in,
                              void* d_out, int out_size, void* d_ws, size_t ws_size,
                              hipStream_t stream) {
    const float* S     = (const float*)d_in[0];
    const float* L     = (const float*)d_in[1];
    const float* C     = (const float*)d_in[2];
    const float* Y     = (const float*)d_in[3];
    const float* M     = (const float*)d_in[4];
    const float* psi   = (const float*)d_in[5];
    const float* gA    = (const float*)d_in[6];
    const float* wgd   = (const float*)d_in[7];
    const float* wgs   = (const float*)d_in[8];
    const float* lsz   = (const float*)d_in[9];
    const float* b0    = (const float*)d_in[10];
    const float* bZ    = (const float*)d_in[11];
    const float* bbins = (const float*)d_in[12];
    const float* wbd   = (const float*)d_in[13];
    const float* wbs   = (const float*)d_in[14];
    const float* bT    = (const float*)d_in[15];

    const int NT    = in_sizes[0];        // N*T = 4194304
    const int n_seq = NT / T_LEN;         // 32768

    // real outputs
    float* zf = (float*)d_out;
    float* zv = zf + NT;
    float* ll = zf + 2 * (size_t)NT;

    // dummy outputs for the slope-experiment pass (d_ws scratch)
    float* zf_d = (float*)d_ws;
    float* zv_d = zf_d + NT;
    float* ll_d = zf_d + 2 * (size_t)NT;

    const int threads = 256;
    const int blocks  = (n_seq * 4) / threads;   // 512

    // ---- pass 1 (dummy, identical work) ----
    hipMemsetAsync((void*)ll_d, 0, sizeof(float), stream);
    k_fused<<<blocks, threads, 0, stream>>>(
        reinterpret_cast<const float4*>(S),
        reinterpret_cast<const float4*>(Y),
        reinterpret_cast<const float4*>(M),
        reinterpret_cast<const float4*>(C),
        reinterpret_cast<const float4*>(L),
        reinterpret_cast<const float4*>(wgd),
        reinterpret_cast<const float4*>(wbd),
        reinterpret_cast<const float4*>(wgs),
        reinterpret_cast<const float4*>(wbs),
        psi, gA, lsz, b0, bZ, bbins, bT,
        zf_d, zv_d, ll_d);

    // ---- pass 2 (real) ----
    hipMemsetAsync((void*)ll, 0, sizeof(float), stream);
    k_fused<<<blocks, threads, 0, stream>>>(
        reinterpret_cast<const float4*>(S),
        reinterpret_cast<const float4*>(Y),
        reinterpret_cast<const float4*>(M),
        reinterpret_cast<const float4*>(C),
        reinterpret_cast<const float4*>(L),
        reinterpret_cast<const float4*>(wgd),
        reinterpret_cast<const float4*>(wbd),
        reinterpret_cast<const float4*>(wgs),
        reinterpret_cast<const float4*>(wbs),
        psi, gA, lsz, b0, bZ, bbins, bT,
        zf, zv, ll);
}

// Round 8
// 234.643 us; speedup vs baseline: 1.4470x; 1.4470x over previous
//
#include <hip/hip_runtime.h>

#define T_LEN 128
#define NB_BINS 15

// ---------------------------------------------------------------------------
// k_static: per-sequence static dots gs/bs -> workspace (tiny)
// ---------------------------------------------------------------------------
__global__ __launch_bounds__(256) void k_static(
    const float4* __restrict__ C4,
    const float4* __restrict__ wgs4,
    const float4* __restrict__ wbs4,
    float* __restrict__ gs_out, float* __restrict__ bs_out, int n_seq)
{
    int n = blockIdx.x * blockDim.x + threadIdx.x;
    if (n >= n_seq) return;
    float gs = 0.0f, bs = 0.0f;
    #pragma unroll
    for (int i = 0; i < 4; ++i) {
        float4 c  = C4[n * 4 + i];
        float4 wg = wgs4[i];
        float4 wb = wbs4[i];
        gs += c.x * wg.x + c.y * wg.y + c.z * wg.z + c.w * wg.w;
        bs += c.x * wb.x + c.y * wb.y + c.z * wb.z + c.w * wb.w;
    }
    gs_out[n] = gs;
    bs_out[n] = bs;
}

// ---------------------------------------------------------------------------
// k_pre: ONE grid-wide contiguous front over L rows (the m13-copy shape).
// 8 lanes/row -> 1KiB contiguous per wave-instruction, one-ahead prefetch.
// lane0 of each row-group side-loads s,y,m (8 consecutive floats per wave)
// and writes packed float4(a, c, y, m) t-major: staged[t*N + n].
//   a = gA*s + gd + gs
//   c = b0 + bin + bd + bs + bT*t/30
// The t-major 16B writes stay within a ~1MB active window (front-coherent)
// so L2 assembles full lines before DRAM writeback.
// ---------------------------------------------------------------------------
__global__ __launch_bounds__(256) void k_pre(
    const float4* __restrict__ L4,
    const float*  __restrict__ S,
    const float*  __restrict__ Y,
    const float*  __restrict__ M,
    const float*  __restrict__ gs_in,
    const float*  __restrict__ bs_in,
    const float4* __restrict__ wgd4,
    const float4* __restrict__ wbd4,
    const float*  __restrict__ p_gA,
    const float*  __restrict__ p_b0,
    const float*  __restrict__ p_bbins,
    const float*  __restrict__ p_bT,
    float4* __restrict__ staged,
    int total_rows, int Nseq)
{
    __shared__ float sbins[NB_BINS];
    if (threadIdx.x < NB_BINS) sbins[threadIdx.x] = p_bbins[threadIdx.x];
    __syncthreads();

    const float gA   = p_gA[0];
    const float b0   = p_b0[0];
    const float bT30 = p_bT[0] * (1.0f / 30.0f);

    const int tid   = blockIdx.x * blockDim.x + threadIdx.x;
    const int lane8 = tid & 7;
    const float4 wg = wgd4[lane8];
    const float4 wb = wbd4[lane8];

    const int group   = tid >> 3;
    const int ngroups = (gridDim.x * blockDim.x) >> 3;   // 65536 rows/front

    // one-ahead prefetch of L vector and the lane0 scalars
    int row = group;
    float4 v = L4[(size_t)row * 8 + lane8];
    float s_v = 0.0f, y_v = 0.0f, m_v = 0.0f;
    if (lane8 == 0) { s_v = S[row]; y_v = Y[row]; m_v = M[row]; }

    for (; row < total_rows; row += ngroups) {
        const int nrow = row + ngroups;
        float4 vn = v;
        float sn = s_v, yn = y_v, mn = m_v;
        if (nrow < total_rows) {
            vn = L4[(size_t)nrow * 8 + lane8];
            if (lane8 == 0) { sn = S[nrow]; yn = Y[nrow]; mn = M[nrow]; }
        }

        float g = v.x * wg.x + v.y * wg.y + v.z * wg.z + v.w * wg.w;
        float b = v.x * wb.x + v.y * wb.y + v.z * wb.z + v.w * wb.w;
        #pragma unroll
        for (int off = 1; off < 8; off <<= 1) {
            g += __shfl_xor(g, off, 64);
            b += __shfl_xor(b, off, 64);
        }

        if (lane8 == 0) {
            const int n = row >> 7;
            const int t = row & 127;
            int cnt = (int)fmaxf(0.0f, fminf(14.0f,
                          ceilf(fmaf(s_v, 3.0f, 7.5f)) - 1.0f));
            const float a = gA * s_v + g + gs_in[n];
            const float c = b0 + sbins[cnt] + b + bs_in[n] + bT30 * (float)t;
            staged[(size_t)t * Nseq + n] = make_float4(a, c, y_v, m_v);
        }
        v = vn; s_v = sn; y_v = yn; m_v = mn;
    }
}

// ---------------------------------------------------------------------------
// k_scan: 4 lanes/seq, 64 seqs/block, 512 blocks (2048 waves, 2/SIMD).
// t-major staged reads: one wave-instruction = 16 consecutive seqs x 16B
// = 256B dense; the whole grid walks t-slabs in lockstep (one front).
// Quad = 16 steps, processed as two 8-step halves with prefetch.
// Lane s stashes chunk s (steps 4s..4s+3) -> 64B-dense n-major writes.
// ll lane-specialized (each step counted exactly once per group).
// ---------------------------------------------------------------------------
__global__ __launch_bounds__(256) void k_scan(
    const float4* __restrict__ staged,
    const float*  __restrict__ p_psi,
    const float*  __restrict__ p_lsz,
    const float*  __restrict__ p_bZ,
    float4* __restrict__ Zf4,
    float4* __restrict__ Zv4,
    float*  __restrict__ ll_out,
    int Nseq)
{
    const int tid = threadIdx.x;
    const int g   = tid >> 2;           // local seq 0..63
    const int s   = tid & 3;            // chunk-lane
    const int n   = blockIdx.x * 64 + g;

    const float psi  = p_psi[0];
    const float e    = __expf(p_lsz[0]);
    const float sig2 = e * e;
    const float bZ   = p_bZ[0];
    const float psi2 = psi * psi;
    const float bZ2  = bZ * bZ;

    float zm = 0.0f, zvv = 1.0f, ll = 0.0f;
    float m0 = 0.f, m1 = 0.f, m2 = 0.f, m3 = 0.f;
    float v0 = 0.f, v1 = 0.f, v2 = 0.f, v3 = 0.f;

    const size_t NS = (size_t)Nseq;

#define LOADH(A,B,C,D,E,F,G,H, tb) do {                                   \
        const float4* p = staged + (size_t)(tb) * NS + n;                 \
        A = p[0];      B = p[NS];     C = p[2*NS];  D = p[3*NS];          \
        E = p[4*NS];   F = p[5*NS];   G = p[6*NS];  H = p[7*NS];          \
    } while (0)

    // one scan step; lane whose chunk==CH stashes into slot SM/SV and adds ll
#define CSTEP(PK, CH, SM, SV) do {                                        \
        const float zpm = fmaf(psi, zm, PK.x);                            \
        const float zpv = fmaf(psi2, zvv, sig2);                          \
        float logit = fmaf(bZ, zpm, PK.y);                                \
        logit = fminf(fmaxf(logit, -20.0f), 20.0f);                       \
        const float prob = __builtin_amdgcn_rcpf(1.0f + __expf(-logit));  \
        const float grad = (PK.z - prob) * bZ * PK.w;                     \
        const float hess = fmaf(bZ2 * prob * (1.0f - prob), PK.w, 1e-6f); \
        const float pvv  = __builtin_amdgcn_rcpf(                         \
                             __builtin_amdgcn_rcpf(zpv + 1e-8f) + hess);  \
        const float pmm  = fmaf(pvv, grad, zpm);                          \
        if (s == (CH)) {                                                  \
            SM = pmm; SV = pvv;                                           \
            ll += (PK.z * __logf(prob + 1e-10f)                           \
                 + (1.0f - PK.z) * __logf(1.0f - prob + 1e-10f)) * PK.w;  \
        }                                                                 \
        zm = pmm; zvv = pvv;                                              \
    } while (0)

    // compute an 8-step half covering chunks c0 (first 4) and c1 (last 4)
#define COMPH(A,B,C,D,E,F,G,H, c0, c1) do {                               \
        CSTEP(A, c0, m0, v0); CSTEP(B, c0, m1, v1);                       \
        CSTEP(C, c0, m2, v2); CSTEP(D, c0, m3, v3);                       \
        CSTEP(E, c1, m0, v0); CSTEP(F, c1, m1, v1);                       \
        CSTEP(G, c1, m2, v2); CSTEP(H, c1, m3, v3);                       \
    } while (0)

    float4 P0, P1, P2, P3, P4, P5, P6, P7;    // current/next half A
    float4 Q0, Q1, Q2, Q3, Q4, Q5, Q6, Q7;    // half B

    LOADH(P0,P1,P2,P3,P4,P5,P6,P7, 0);        // quad0 half0

    for (int Q = 0; Q < 8; ++Q) {
        const int tb1 = 16 * Q + 8;
        LOADH(Q0,Q1,Q2,Q3,Q4,Q5,Q6,Q7, tb1);          // half1 of quad Q
        COMPH(P0,P1,P2,P3,P4,P5,P6,P7, 0, 1);          // chunks 0,1

        const int tb0 = (Q < 7) ? (16 * Q + 16) : 112; // prefetch next half0
        LOADH(P0,P1,P2,P3,P4,P5,P6,P7, tb0);
        COMPH(Q0,Q1,Q2,Q3,Q4,Q5,Q6,Q7, 2, 3);          // chunks 2,3

        // n-major dense write: group of 4 lanes covers 64B consecutive
        const size_t ob = (size_t)n * 32 + Q * 4 + s;
        Zf4[ob] = make_float4(m0, m1, m2, m3);
        Zv4[ob] = make_float4(v0, v1, v2, v3);
    }
#undef COMPH
#undef CSTEP
#undef LOADH

    // each step's ll counted exactly once across the wave -> full reduce
    #pragma unroll
    for (int off = 1; off < 64; off <<= 1) ll += __shfl_xor(ll, off, 64);
    if ((tid & 63) == 0) atomicAdd(ll_out, ll);
}

// ---------------------------------------------------------------------------
extern "C" void kernel_launch(void* const* d_in, const int* in_sizes, int n_in,
                              void* d_out, int out_size, void* d_ws, size_t ws_size,
                              hipStream_t stream) {
    const float* S     = (const float*)d_in[0];
    const float* L     = (const float*)d_in[1];
    const float* C     = (const float*)d_in[2];
    const float* Y     = (const float*)d_in[3];
    const float* M     = (const float*)d_in[4];
    const float* psi   = (const float*)d_in[5];
    const float* gA    = (const float*)d_in[6];
    const float* wgd   = (const float*)d_in[7];
    const float* wgs   = (const float*)d_in[8];
    const float* lsz   = (const float*)d_in[9];
    const float* b0    = (const float*)d_in[10];
    const float* bZ    = (const float*)d_in[11];
    const float* bbins = (const float*)d_in[12];
    const float* wbd   = (const float*)d_in[13];
    const float* wbs   = (const float*)d_in[14];
    const float* bT    = (const float*)d_in[15];

    const int NT    = in_sizes[0];        // N*T = 4194304
    const int n_seq = NT / T_LEN;         // 32768

    float* zf = (float*)d_out;
    float* zv = zf + NT;
    float* ll = zf + 2 * (size_t)NT;

    float4* staged = (float4*)d_ws;                 // 67 MB t-major staging
    float*  gs_ws  = (float*)(staged + NT);
    float*  bs_ws  = gs_ws + n_seq;

    hipMemsetAsync((void*)ll, 0, sizeof(float), stream);

    // statics
    k_static<<<(n_seq + 255) / 256, 256, 0, stream>>>(
        reinterpret_cast<const float4*>(C),
        reinterpret_cast<const float4*>(wgs),
        reinterpret_cast<const float4*>(wbs),
        gs_ws, bs_ws, n_seq);

    // front-shaped precompute + t-major transpose
    k_pre<<<2048, 256, 0, stream>>>(
        reinterpret_cast<const float4*>(L),
        S, Y, M, gs_ws, bs_ws,
        reinterpret_cast<const float4*>(wgd),
        reinterpret_cast<const float4*>(wbd),
        gA, b0, bbins, bT,
        staged, NT, n_seq);

    // front-shaped t-major scan
    k_scan<<<n_seq / 64, 256, 0, stream>>>(
        staged, psi, lsz, bZ,
        reinterpret_cast<float4*>(zf),
        reinterpret_cast<float4*>(zv),
        ll, n_seq);
}